// Round 5
// baseline (211.921 us; speedup 1.0000x reference)
//
#include <hip/hip_runtime.h>
#include <hip/hip_cooperative_groups.h>
#include <math.h>

namespace cg = cooperative_groups;

#define S_LEN 8192
#define HDIM  4096
#define H4    (HDIM / 4)      // 1024 float4 per row
#define BLK   512
#define NWAVE 8
#define RB 4                  // rows per barrier batch (RB=4 measured == RB=8)
#define GRID 512              // cooperative grid (2 blocks/CU on 256 CUs)
#define RPB  (S_LEN / GRID)   // 16 rows per block
#define SUMB 32               // colsum blocks in phase 2 / fallback finalize
#define FB_ATTN 8

__device__ __forceinline__ float wave_reduce_sum(float x) {
#pragma unroll
  for (int o = 32; o > 0; o >>= 1) x += __shfl_xor(x, o, 64);
  return x;
}
__device__ __forceinline__ float wave_reduce_max(float x) {
#pragma unroll
  for (int o = 32; o > 0; o >>= 1) x = fmaxf(x, __shfl_xor(x, o, 64));
  return x;
}

// ---------------- fused cooperative kernel ----------------
// phase 1: GEMV + online softmax + weighted row accum (16 rows/block)
// grid.sync()
// phase 2: stats from mb/lb; attn for own rows; colsum by blocks 0..31
__global__ __launch_bounds__(BLK, 4) void fused_k(
    const float* __restrict__ enc, const float* __restrict__ hidden,
    float* __restrict__ energies, float* __restrict__ mb, float* __restrict__ lb,
    float* __restrict__ opart, float* __restrict__ out) {
  const int t = threadIdx.x;
  const int b = blockIdx.x;
  const int row0 = b * RPB;
  const int wid = t >> 6;
  const bool lane0 = (t & 63) == 0;

  __shared__ float red[RB * NWAVE];
  __shared__ float smax[NWAVE], ssum[NWAVE];
  __shared__ float4 sred[BLK];

  // ---- phase 1 ----
  const float4* hv = (const float4*)hidden;
  float hh[8];
  {
    const float4 h0 = hv[t];
    const float4 h1 = hv[t + BLK];
    hh[0] = h0.x; hh[1] = h0.y; hh[2] = h0.z; hh[3] = h0.w;
    hh[4] = h1.x; hh[5] = h1.y; hh[6] = h1.z; hh[7] = h1.w;
  }
  float aa[8] = {0.f, 0.f, 0.f, 0.f, 0.f, 0.f, 0.f, 0.f};
  float m = -INFINITY, l = 0.f;
  const float4* encv = (const float4*)enc;

  for (int r0 = row0; r0 < row0 + RPB; r0 += RB) {
    float vv[RB][8];
    float d[RB];
#pragma unroll
    for (int r = 0; r < RB; ++r) {
      const float4* rp = encv + (size_t)(r0 + r) * H4;
      const float4 x0 = rp[t];
      const float4 x1 = rp[t + BLK];
      vv[r][0] = x0.x; vv[r][1] = x0.y; vv[r][2] = x0.z; vv[r][3] = x0.w;
      vv[r][4] = x1.x; vv[r][5] = x1.y; vv[r][6] = x1.z; vv[r][7] = x1.w;
    }
#pragma unroll
    for (int r = 0; r < RB; ++r) {
      float s = 0.f;
#pragma unroll
      for (int k = 0; k < 8; ++k) s = fmaf(vv[r][k], hh[k], s);
      d[r] = s;
    }
#pragma unroll
    for (int o = 32; o > 0; o >>= 1) {
#pragma unroll
      for (int r = 0; r < RB; ++r) d[r] += __shfl_xor(d[r], o, 64);
    }
    if (lane0) {
#pragma unroll
      for (int r = 0; r < RB; ++r) red[r * NWAVE + wid] = d[r];
    }
    __syncthreads();
    float e[RB];
#pragma unroll
    for (int r = 0; r < RB; ++r) {
      const float4 q0 = *(const float4*)&red[r * NWAVE];
      const float4 q1 = *(const float4*)&red[r * NWAVE + 4];
      e[r] = (q0.x + q0.y + q0.z + q0.w) + (q1.x + q1.y + q1.z + q1.w);
    }
    __syncthreads();
    if (t == 0) {
#pragma unroll
      for (int r = 0; r < RB; ++r) energies[r0 + r] = e[r];
    }
    float mn = m;
#pragma unroll
    for (int r = 0; r < RB; ++r) mn = fmaxf(mn, e[r]);
    const float sc = __expf(m - mn);
    float w[RB];
    float lsum = 0.f;
#pragma unroll
    for (int r = 0; r < RB; ++r) { w[r] = __expf(e[r] - mn); lsum += w[r]; }
    l = l * sc + lsum;
#pragma unroll
    for (int k = 0; k < 8; ++k) {
      float a = aa[k] * sc;
#pragma unroll
      for (int r = 0; r < RB; ++r) a = fmaf(w[r], vv[r][k], a);
      aa[k] = a;
    }
    m = mn;
  }

  {
    float4* op = (float4*)(opart + (size_t)b * HDIM);
    op[t]       = make_float4(aa[0], aa[1], aa[2], aa[3]);
    op[t + BLK] = make_float4(aa[4], aa[5], aa[6], aa[7]);
    if (t == 0) { mb[b] = m; lb[b] = l; }
  }

  cg::this_grid().sync();

  // ---- phase 2: stats (Gu == GRID == 512 == BLK threads, one entry each) ----
  const float mbt = mb[t];
  float mv = wave_reduce_max(mbt);
  if (lane0) smax[wid] = mv;
  __syncthreads();
  float gm = smax[0];
#pragma unroll
  for (int i = 1; i < NWAVE; ++i) gm = fmaxf(gm, smax[i]);

  float lv = wave_reduce_sum(lb[t] * __expf(mbt - gm));
  if (lane0) ssum[wid] = lv;
  __syncthreads();
  float L = ssum[0];
#pragma unroll
  for (int i = 1; i < NWAVE; ++i) L += ssum[i];
  const float invL = 1.f / L;

  // attn for this block's own rows (energies L2-hot)
  if (t < RPB) {
    out[HDIM + row0 + t] = __expf(energies[row0 + t] - gm) * invL;
  }

  // colsum: blocks 0..SUMB-1, each owns 32 float4-cols; 16 g-groups
  if (b < SUMB) {
    const int c  = b * SUMB + (t & 31);
    const int g0 = t >> 5;
    float4 acc = {0.f, 0.f, 0.f, 0.f};
    for (int g = g0; g < GRID; g += 16) {
      const float w = __expf(mb[g] - gm) * invL;
      const float4 v = ((const float4*)opart)[(size_t)g * H4 + c];
      acc.x = fmaf(w, v.x, acc.x);
      acc.y = fmaf(w, v.y, acc.y);
      acc.z = fmaf(w, v.z, acc.z);
      acc.w = fmaf(w, v.w, acc.w);
    }
    sred[t] = acc;
    __syncthreads();
    if (t < 32) {
      float4 s = sred[t];
#pragma unroll
      for (int q = 1; q < 16; ++q) {
        const float4 v = sred[q * 32 + t];
        s.x += v.x; s.y += v.y; s.z += v.z; s.w += v.w;
      }
      ((float4*)out)[b * SUMB + t] = s;
    }
  }
}

// ---------------- fallback two-kernel path (proven in R4) ----------------
#define P1_BLOCK 512
#define P1_WAVES 8
#define RBF 8

__global__ __launch_bounds__(P1_BLOCK) void pass1_k(
    const float* __restrict__ enc, const float* __restrict__ hidden,
    float* __restrict__ energies, float* __restrict__ mb, float* __restrict__ lb,
    float* __restrict__ opart, int rpb) {
  const int t = threadIdx.x;
  const int b = blockIdx.x;
  const int row0 = b * rpb;
  const int row1 = min(S_LEN, row0 + rpb);

  const float4* hv = (const float4*)hidden;
  float hh[8];
  {
    const float4 h0 = hv[t];
    const float4 h1 = hv[t + P1_BLOCK];
    hh[0] = h0.x; hh[1] = h0.y; hh[2] = h0.z; hh[3] = h0.w;
    hh[4] = h1.x; hh[5] = h1.y; hh[6] = h1.z; hh[7] = h1.w;
  }
  float aa[8] = {0.f, 0.f, 0.f, 0.f, 0.f, 0.f, 0.f, 0.f};
  float m = -INFINITY, l = 0.f;
  __shared__ float red[RBF * P1_WAVES];
  const int wid = t >> 6;
  const bool lane0 = (t & 63) == 0;
  const float4* encv = (const float4*)enc;

  for (int r0 = row0; r0 < row1; r0 += RBF) {
    const int nr = min(RBF, row1 - r0);
    float vv[RBF][8];
    float d[RBF];
#pragma unroll
    for (int r = 0; r < RBF; ++r) {
      float4 x0 = make_float4(0.f, 0.f, 0.f, 0.f);
      float4 x1 = make_float4(0.f, 0.f, 0.f, 0.f);
      if (r < nr) {
        const float4* rp = encv + (size_t)(r0 + r) * H4;
        x0 = rp[t];
        x1 = rp[t + P1_BLOCK];
      }
      vv[r][0] = x0.x; vv[r][1] = x0.y; vv[r][2] = x0.z; vv[r][3] = x0.w;
      vv[r][4] = x1.x; vv[r][5] = x1.y; vv[r][6] = x1.z; vv[r][7] = x1.w;
    }
#pragma unroll
    for (int r = 0; r < RBF; ++r) {
      float s = 0.f;
#pragma unroll
      for (int k = 0; k < 8; ++k) s = fmaf(vv[r][k], hh[k], s);
      d[r] = s;
    }
#pragma unroll
    for (int o = 32; o > 0; o >>= 1) {
#pragma unroll
      for (int r = 0; r < RBF; ++r) d[r] += __shfl_xor(d[r], o, 64);
    }
    if (lane0) {
#pragma unroll
      for (int r = 0; r < RBF; ++r) red[r * P1_WAVES + wid] = d[r];
    }
    __syncthreads();
    float e[RBF];
#pragma unroll
    for (int r = 0; r < RBF; ++r) {
      const float4 q0 = *(const float4*)&red[r * P1_WAVES];
      const float4 q1 = *(const float4*)&red[r * P1_WAVES + 4];
      e[r] = (q0.x + q0.y + q0.z + q0.w) + (q1.x + q1.y + q1.z + q1.w);
    }
    __syncthreads();
    if (t == 0) {
      for (int r = 0; r < nr; ++r) energies[r0 + r] = e[r];
    }
    float mn = m;
#pragma unroll
    for (int r = 0; r < RBF; ++r)
      if (r < nr) mn = fmaxf(mn, e[r]);
    const float sc = __expf(m - mn);
    float w[RBF];
    float lsum = 0.f;
#pragma unroll
    for (int r = 0; r < RBF; ++r) {
      w[r] = (r < nr) ? __expf(e[r] - mn) : 0.f;
      lsum += w[r];
    }
    l = l * sc + lsum;
#pragma unroll
    for (int k = 0; k < 8; ++k) {
      float a = aa[k] * sc;
#pragma unroll
      for (int r = 0; r < RBF; ++r) a = fmaf(w[r], vv[r][k], a);
      aa[k] = a;
    }
    m = mn;
  }

  float4* op = (float4*)(opart + (size_t)b * HDIM);
  op[t]            = make_float4(aa[0], aa[1], aa[2], aa[3]);
  op[t + P1_BLOCK] = make_float4(aa[4], aa[5], aa[6], aa[7]);
  if (t == 0) { mb[b] = m; lb[b] = l; }
}

__global__ __launch_bounds__(256) void finalize_k(
    const float* __restrict__ opart, const float* __restrict__ mb,
    const float* __restrict__ lb, const float* __restrict__ energies,
    float* __restrict__ out, int Gu) {
  const int t = threadIdx.x;
  const int wid = t >> 6;
  const bool lane0 = (t & 63) == 0;
  __shared__ float smax[4], ssum[4];

  float mv = -INFINITY;
  for (int g = t; g < Gu; g += 256) mv = fmaxf(mv, mb[g]);
  mv = wave_reduce_max(mv);
  if (lane0) smax[wid] = mv;
  __syncthreads();
  const float gm = fmaxf(fmaxf(smax[0], smax[1]), fmaxf(smax[2], smax[3]));

  float lv = 0.f;
  for (int g = t; g < Gu; g += 256) lv += lb[g] * __expf(mb[g] - gm);
  lv = wave_reduce_sum(lv);
  if (lane0) ssum[wid] = lv;
  __syncthreads();
  const float invL = 1.f / (ssum[0] + ssum[1] + ssum[2] + ssum[3]);

  if ((int)blockIdx.x < SUMB) {
    const int c  = blockIdx.x * 32 + (t & 31);
    const int g0 = t >> 5;
    float4 acc = {0.f, 0.f, 0.f, 0.f};
    for (int g = g0; g < Gu; g += 8) {
      const float w = __expf(mb[g] - gm) * invL;
      const float4 v = ((const float4*)opart)[(size_t)g * H4 + c];
      acc.x = fmaf(w, v.x, acc.x);
      acc.y = fmaf(w, v.y, acc.y);
      acc.z = fmaf(w, v.z, acc.z);
      acc.w = fmaf(w, v.w, acc.w);
    }
    __shared__ float4 sred[256];
    sred[t] = acc;
    __syncthreads();
    if (t < 32) {
      float4 s = sred[t];
#pragma unroll
      for (int q = 1; q < 8; ++q) {
        const float4 v = sred[q * 32 + t];
        s.x += v.x; s.y += v.y; s.z += v.z; s.w += v.w;
      }
      ((float4*)out)[blockIdx.x * 32 + t] = s;
    }
  } else {
    const int i4 = ((int)blockIdx.x - SUMB) * 256 + t;
    const float4 e = ((const float4*)energies)[i4];
    float4 a;
    a.x = __expf(e.x - gm) * invL;
    a.y = __expf(e.y - gm) * invL;
    a.z = __expf(e.z - gm) * invL;
    a.w = __expf(e.w - gm) * invL;
    ((float4*)(out + HDIM))[i4] = a;
  }
}

extern "C" void kernel_launch(void* const* d_in, const int* in_sizes, int n_in,
                              void* d_out, int out_size, void* d_ws, size_t ws_size,
                              hipStream_t stream) {
  const float* hidden = (const float*)d_in[0];          // [4096] f32
  const float* enc    = (const float*)d_in[1];          // [8192,1,4096] f32
  float* out = (float*)d_out;                           // [4096 output | 8192 attn]
  float* wsf = (float*)d_ws;

  float* energies = wsf;            // 8192
  float* mb       = wsf + 8192;     // up to 1024
  float* lb       = wsf + 9216;     // up to 1024
  float* opart    = wsf + 10240;    // G * 4096

  const size_t avail_f = ws_size / 4;
  int Gmax = (avail_f > 10240) ? (int)((avail_f - 10240) / HDIM) : 1;
  int G = Gmax < GRID ? Gmax : GRID;
  if (G < 1) G = 1;
  const int rpb = (S_LEN + G - 1) / G;
  const int Gu  = (S_LEN + rpb - 1) / rpb;

  // cooperative path: requires exact geometry + full co-residency
  bool coop = (Gu == GRID && rpb == RPB);
  if (coop) {
    int nb = 0;
    if (hipOccupancyMaxActiveBlocksPerMultiprocessor(
            &nb, (const void*)fused_k, BLK, 0) != hipSuccess) nb = 0;
    int dev = 0, cus = 0;
    hipGetDevice(&dev);
    hipDeviceGetAttribute(&cus, hipDeviceAttributeMultiprocessorCount, dev);
    if ((long)nb * cus < GRID) coop = false;
  }

  if (coop) {
    void* args[] = {(void*)&enc, (void*)&hidden, (void*)&energies,
                    (void*)&mb, (void*)&lb, (void*)&opart, (void*)&out};
    if (hipLaunchCooperativeKernel((const void*)fused_k, dim3(GRID), dim3(BLK),
                                   args, 0, stream) == hipSuccess)
      return;
  }

  pass1_k<<<Gu, P1_BLOCK, 0, stream>>>(enc, hidden, energies, mb, lb, opart, rpb);
  finalize_k<<<SUMB + FB_ATTN, 256, 0, stream>>>(opart, mb, lb, energies, out, Gu);
}

// Round 6
// 209.521 us; speedup vs baseline: 1.0115x; 1.0115x over previous
//
#include <hip/hip_runtime.h>
#include <math.h>

#define S_LEN 8192
#define HDIM  4096
#define H4    1024            // float4 per row
#define ABLK  256             // pass A block size
#define AGRID 256             // pass A blocks (1 per CU)
#define AWPB  4               // waves per block
#define NWAVES (AGRID * AWPB) // 1024 waves
#define RPW   (S_LEN / NWAVES)// 8 rows per wave
#define CBLK  128             // finalize colsum blocks (8 float4-cols each)
#define FB_ATTN 8             // 8 blocks * 256 thr * 4 = 8192 attn elems

__device__ __forceinline__ float wave_reduce_sum(float x) {
#pragma unroll
  for (int o = 32; o > 0; o >>= 1) x += __shfl_xor(x, o, 64);
  return x;
}
__device__ __forceinline__ float wave_reduce_max(float x) {
#pragma unroll
  for (int o = 32; o > 0; o >>= 1) x = fmaxf(x, __shfl_xor(x, o, 64));
  return x;
}

// Pass A: per-WAVE fused GEMV + online softmax + weighted row accumulation.
// No block barriers in the streaming loop: each wave owns RPW rows end-to-end.
// Lane l covers row elements [l*4 + k*256 .. ] (16 float4 per lane, 64 acc floats).
__global__ __launch_bounds__(ABLK) void wavegemv_k(
    const float* __restrict__ enc, const float* __restrict__ hidden,
    float* __restrict__ energies, float* __restrict__ mw, float* __restrict__ lw,
    float* __restrict__ opart) {
  const int t = threadIdx.x;
  const int lane = t & 63;
  const int wid = t >> 6;

  __shared__ float4 hs[H4];   // 16 KB staged hidden
  {
    const float4* hv = (const float4*)hidden;
#pragma unroll
    for (int k = 0; k < 4; ++k) hs[t + k * ABLK] = hv[t + k * ABLK];
  }
  __syncthreads();            // only barrier in the kernel

  const int gw = blockIdx.x * AWPB + wid;   // 0..1023
  const int r0 = gw * RPW;

  float4 acc[16];
#pragma unroll
  for (int k = 0; k < 16; ++k) acc[k] = make_float4(0.f, 0.f, 0.f, 0.f);
  float m = -INFINITY, l = 0.f;

  const float4* encv = (const float4*)enc;
  for (int r = r0; r < r0 + RPW; ++r) {
    const float4* rp = encv + (size_t)r * H4 + lane;
    float4 v[16];
#pragma unroll
    for (int k = 0; k < 16; ++k) v[k] = rp[k * 64];   // 16 dwordx4 in flight
    float d = 0.f;
#pragma unroll
    for (int k = 0; k < 16; ++k) {
      const float4 h = hs[lane + k * 64];             // conflict-free b128
      d = fmaf(v[k].x, h.x, d);
      d = fmaf(v[k].y, h.y, d);
      d = fmaf(v[k].z, h.z, d);
      d = fmaf(v[k].w, h.w, d);
    }
    d = wave_reduce_sum(d);   // e identical in all 64 lanes after butterfly
    if (lane == 0) energies[r] = d;
    if (d > m) {              // wave-uniform branch: rescale only when max grows
      const float sc = __expf(m - d);   // first row: exp(-inf)=0, acc/l are 0
      l *= sc;
#pragma unroll
      for (int k = 0; k < 16; ++k) {
        acc[k].x *= sc; acc[k].y *= sc; acc[k].z *= sc; acc[k].w *= sc;
      }
      m = d;
    }
    const float w = __expf(d - m);
    l += w;
#pragma unroll
    for (int k = 0; k < 16; ++k) {
      acc[k].x = fmaf(w, v[k].x, acc[k].x);
      acc[k].y = fmaf(w, v[k].y, acc[k].y);
      acc[k].z = fmaf(w, v[k].z, acc[k].z);
      acc[k].w = fmaf(w, v[k].w, acc[k].w);
    }
  }

  float4* op = (float4*)(opart + (size_t)gw * HDIM);
#pragma unroll
  for (int k = 0; k < 16; ++k) op[lane + k * 64] = acc[k];
  if (lane == 0) { mw[gw] = m; lw[gw] = l; }
}

// Finalize: every block recomputes (gm, invL) from the 1024 (m,l) pairs and a
// weight table in LDS. Blocks [0,CBLK): colsum of opart, 8 float4-cols each,
// each out element written exactly once. Blocks [CBLK,CBLK+FB_ATTN): attn.
__global__ __launch_bounds__(256) void finalize_k(
    const float* __restrict__ opart, const float* __restrict__ mw,
    const float* __restrict__ lw, const float* __restrict__ energies,
    float* __restrict__ out) {
  const int t = threadIdx.x;
  const int b = blockIdx.x;
  const int wid = t >> 6;
  const bool lane0 = (t & 63) == 0;

  __shared__ float wg[NWAVES];          // 4 KB weight table
  __shared__ float smax[4], ssum[4];

  float mv = -INFINITY;
  for (int g = t; g < NWAVES; g += 256) mv = fmaxf(mv, mw[g]);
  mv = wave_reduce_max(mv);
  if (lane0) smax[wid] = mv;
  __syncthreads();
  const float gm = fmaxf(fmaxf(smax[0], smax[1]), fmaxf(smax[2], smax[3]));

  float lv = 0.f;
  for (int g = t; g < NWAVES; g += 256) lv += lw[g] * __expf(mw[g] - gm);
  lv = wave_reduce_sum(lv);
  if (lane0) ssum[wid] = lv;
  __syncthreads();
  const float invL = 1.f / (ssum[0] + ssum[1] + ssum[2] + ssum[3]);

  for (int g = t; g < NWAVES; g += 256) wg[g] = __expf(mw[g] - gm) * invL;
  __syncthreads();

  if (b < CBLK) {
    const int c  = b * 8 + (t & 7);     // float4-column 0..1023
    const int g0 = t >> 3;              // 32 g-groups
    float4 acc = {0.f, 0.f, 0.f, 0.f};
    for (int g = g0; g < NWAVES; g += 32) {
      const float w = wg[g];
      const float4 v = ((const float4*)opart)[(size_t)g * H4 + c];
      acc.x = fmaf(w, v.x, acc.x);
      acc.y = fmaf(w, v.y, acc.y);
      acc.z = fmaf(w, v.z, acc.z);
      acc.w = fmaf(w, v.w, acc.w);
    }
    __shared__ float4 sred[256];
    sred[t] = acc;
    __syncthreads();
    if (t < 8) {
      float4 s = sred[t];
#pragma unroll
      for (int q = 1; q < 32; ++q) {
        const float4 v = sred[q * 8 + t];
        s.x += v.x; s.y += v.y; s.z += v.z; s.w += v.w;
      }
      ((float4*)out)[b * 8 + t] = s;
    }
  } else {
    const int i4 = (b - CBLK) * 256 + t;          // float4 idx into [0,2048)
    const float4 e = ((const float4*)energies)[i4];
    float4 a;
    a.x = __expf(e.x - gm) * invL;
    a.y = __expf(e.y - gm) * invL;
    a.z = __expf(e.z - gm) * invL;
    a.w = __expf(e.w - gm) * invL;
    ((float4*)(out + HDIM))[i4] = a;
  }
}

extern "C" void kernel_launch(void* const* d_in, const int* in_sizes, int n_in,
                              void* d_out, int out_size, void* d_ws, size_t ws_size,
                              hipStream_t stream) {
  const float* hidden = (const float*)d_in[0];   // [4096] f32
  const float* enc    = (const float*)d_in[1];   // [8192,1,4096] f32
  float* out = (float*)d_out;                    // [4096 output | 8192 attn]
  float* wsf = (float*)d_ws;

  // workspace layout (floats): energies 8192 | mw 1024 | lw 1024 | opart 1024*4096
  float* energies = wsf;
  float* mw       = wsf + 8192;
  float* lw       = wsf + 8192 + 1024;
  float* opart    = wsf + 8192 + 2048;           // 16 MiB

  wavegemv_k<<<AGRID, ABLK, 0, stream>>>(enc, hidden, energies, mw, lw, opart);
  finalize_k<<<CBLK + FB_ATTN, 256, 0, stream>>>(opart, mw, lw, energies, out);
}

// Round 7
// 203.757 us; speedup vs baseline: 1.0401x; 1.0283x over previous
//
#include <hip/hip_runtime.h>
#include <math.h>

#define S_LEN 8192
#define HDIM  4096
#define H4    1024            // float4 per row
#define ABLK  256             // pass A block size (4 waves)
#define AGRID 512             // 2 blocks/CU -> 2 waves/SIMD
#define AWPB  4               // waves per block
#define NWTOT (AGRID * AWPB)  // 2048 waves
#define RPW   (S_LEN / NWTOT) // 4 rows per wave
#define NPART AGRID           // 512 block-partials after cross-wave combine
#define CBLK  128             // finalize colsum blocks (8 float4-cols each)
#define FB_ATTN 8             // 8 blocks * 256 thr * 4 = 8192 attn elems

__device__ __forceinline__ float wave_reduce_sum(float x) {
#pragma unroll
  for (int o = 32; o > 0; o >>= 1) x += __shfl_xor(x, o, 64);
  return x;
}
__device__ __forceinline__ float wave_reduce_max(float x) {
#pragma unroll
  for (int o = 32; o > 0; o >>= 1) x = fmaxf(x, __shfl_xor(x, o, 64));
  return x;
}

// Pass A: per-WAVE fused GEMV + online softmax + weighted row accumulation,
// then a cross-wave LDS combine so each BLOCK emits one 16 KB partial.
// lds[] is time-shared: hidden stage (16 KB) during streaming, then the
// 4-wave accumulator exchange (64 KB) for the combine.
__global__ __launch_bounds__(ABLK) void wavegemv_k(
    const float* __restrict__ enc, const float* __restrict__ hidden,
    float* __restrict__ energies, float* __restrict__ mb, float* __restrict__ lb,
    float* __restrict__ opart) {
  const int t = threadIdx.x;
  const int lane = t & 63;
  const int wid = t >> 6;

  __shared__ float4 lds[4 * H4];        // 64 KB, aliased
  __shared__ float sm[AWPB], sl[AWPB];

  float4* hs = lds;                     // [H4] hidden stage
  {
    const float4* hv = (const float4*)hidden;
#pragma unroll
    for (int k = 0; k < 4; ++k) hs[t + k * ABLK] = hv[t + k * ABLK];
  }
  __syncthreads();

  const int gw = blockIdx.x * AWPB + wid;   // 0..2047
  const int r0 = gw * RPW;

  float4 acc[16];
#pragma unroll
  for (int k = 0; k < 16; ++k) acc[k] = make_float4(0.f, 0.f, 0.f, 0.f);
  float m = -INFINITY, l = 0.f;

  const float4* encv = (const float4*)enc;
  for (int r = r0; r < r0 + RPW; ++r) {
    const float4* rp = encv + (size_t)r * H4 + lane;
    float4 v[16];
#pragma unroll
    for (int k = 0; k < 16; ++k) v[k] = rp[k * 64];   // 16 dwordx4 in flight
    float d = 0.f;
#pragma unroll
    for (int k = 0; k < 16; ++k) {
      const float4 h = hs[lane + k * 64];             // conflict-free b128
      d = fmaf(v[k].x, h.x, d);
      d = fmaf(v[k].y, h.y, d);
      d = fmaf(v[k].z, h.z, d);
      d = fmaf(v[k].w, h.w, d);
    }
    d = wave_reduce_sum(d);   // e uniform across the wave after butterfly
    if (lane == 0) energies[r] = d;
    if (d > m) {              // wave-uniform: rescale only when max grows
      const float sc = __expf(m - d);   // first row: exp(-inf)=0; acc/l are 0
      l *= sc;
#pragma unroll
      for (int k = 0; k < 16; ++k) {
        acc[k].x *= sc; acc[k].y *= sc; acc[k].z *= sc; acc[k].w *= sc;
      }
      m = d;
    }
    const float w = __expf(d - m);
    l += w;
#pragma unroll
    for (int k = 0; k < 16; ++k) {
      acc[k].x = fmaf(w, v[k].x, acc[k].x);
      acc[k].y = fmaf(w, v[k].y, acc[k].y);
      acc[k].z = fmaf(w, v[k].z, acc[k].z);
      acc[k].w = fmaf(w, v[k].w, acc[k].w);
    }
  }

  // ---- cross-wave combine (4 waves -> 1 block partial) ----
  __syncthreads();                       // hs no longer needed; reuse lds
#pragma unroll
  for (int k = 0; k < 16; ++k) lds[wid * H4 + lane + k * 64] = acc[k];
  if (lane == 0) { sm[wid] = m; sl[wid] = l; }
  __syncthreads();

  const float M = fmaxf(fmaxf(sm[0], sm[1]), fmaxf(sm[2], sm[3]));
  float cw[AWPB];
#pragma unroll
  for (int w = 0; w < AWPB; ++w) cw[w] = __expf(sm[w] - M);

  float4* op = (float4*)(opart + (size_t)blockIdx.x * HDIM);
#pragma unroll
  for (int p = 0; p < 4; ++p) {
    const int idx = t + p * ABLK;        // 0..1023
    float4 s = {0.f, 0.f, 0.f, 0.f};
#pragma unroll
    for (int w = 0; w < AWPB; ++w) {
      const float4 v = lds[w * H4 + idx];
      s.x = fmaf(cw[w], v.x, s.x);
      s.y = fmaf(cw[w], v.y, s.y);
      s.z = fmaf(cw[w], v.z, s.z);
      s.w = fmaf(cw[w], v.w, s.w);
    }
    op[idx] = s;
  }
  if (t == 0) {
    mb[blockIdx.x] = M;
    lb[blockIdx.x] = sl[0] * cw[0] + sl[1] * cw[1] + sl[2] * cw[2] + sl[3] * cw[3];
  }
}

// Finalize: every block recomputes (gm, invL) from the 512 (m,l) pairs and a
// weight table in LDS. Blocks [0,CBLK): colsum of opart, 8 float4-cols each,
// each out element written exactly once. Blocks [CBLK,CBLK+FB_ATTN): attn.
__global__ __launch_bounds__(256) void finalize_k(
    const float* __restrict__ opart, const float* __restrict__ mb,
    const float* __restrict__ lb, const float* __restrict__ energies,
    float* __restrict__ out) {
  const int t = threadIdx.x;
  const int b = blockIdx.x;
  const int wid = t >> 6;
  const bool lane0 = (t & 63) == 0;

  __shared__ float wg[NPART];           // 2 KB weight table
  __shared__ float smax[4], ssum[4];

  float mv = -INFINITY;
  for (int g = t; g < NPART; g += 256) mv = fmaxf(mv, mb[g]);
  mv = wave_reduce_max(mv);
  if (lane0) smax[wid] = mv;
  __syncthreads();
  const float gm = fmaxf(fmaxf(smax[0], smax[1]), fmaxf(smax[2], smax[3]));

  float lv = 0.f;
  for (int g = t; g < NPART; g += 256) lv += lb[g] * __expf(mb[g] - gm);
  lv = wave_reduce_sum(lv);
  if (lane0) ssum[wid] = lv;
  __syncthreads();
  const float invL = 1.f / (ssum[0] + ssum[1] + ssum[2] + ssum[3]);

  for (int g = t; g < NPART; g += 256) wg[g] = __expf(mb[g] - gm) * invL;
  __syncthreads();

  if (b < CBLK) {
    const int c  = b * 8 + (t & 7);     // float4-column 0..1023
    const int g0 = t >> 3;              // 32 g-groups
    float4 acc = {0.f, 0.f, 0.f, 0.f};
    for (int g = g0; g < NPART; g += 32) {
      const float w = wg[g];
      const float4 v = ((const float4*)opart)[(size_t)g * H4 + c];
      acc.x = fmaf(w, v.x, acc.x);
      acc.y = fmaf(w, v.y, acc.y);
      acc.z = fmaf(w, v.z, acc.z);
      acc.w = fmaf(w, v.w, acc.w);
    }
    __shared__ float4 sred[256];
    sred[t] = acc;
    __syncthreads();
    if (t < 8) {
      float4 s = sred[t];
#pragma unroll
      for (int q = 1; q < 32; ++q) {
        const float4 v = sred[q * 8 + t];
        s.x += v.x; s.y += v.y; s.z += v.z; s.w += v.w;
      }
      ((float4*)out)[b * 8 + t] = s;
    }
  } else {
    const int i4 = (b - CBLK) * 256 + t;          // float4 idx into [0,2048)
    const float4 e = ((const float4*)energies)[i4];
    float4 a;
    a.x = __expf(e.x - gm) * invL;
    a.y = __expf(e.y - gm) * invL;
    a.z = __expf(e.z - gm) * invL;
    a.w = __expf(e.w - gm) * invL;
    ((float4*)(out + HDIM))[i4] = a;
  }
}

extern "C" void kernel_launch(void* const* d_in, const int* in_sizes, int n_in,
                              void* d_out, int out_size, void* d_ws, size_t ws_size,
                              hipStream_t stream) {
  const float* hidden = (const float*)d_in[0];   // [4096] f32
  const float* enc    = (const float*)d_in[1];   // [8192,1,4096] f32
  float* out = (float*)d_out;                    // [4096 output | 8192 attn]
  float* wsf = (float*)d_ws;

  // workspace (floats): energies 8192 | mb 512 | lb 512 | opart 512*4096 (8 MiB)
  float* energies = wsf;
  float* mb       = wsf + 8192;
  float* lb       = wsf + 8192 + 512;
  float* opart    = wsf + 8192 + 1024;

  wavegemv_k<<<AGRID, ABLK, 0, stream>>>(enc, hidden, energies, mb, lb, opart);
  finalize_k<<<CBLK + FB_ATTN, 256, 0, stream>>>(opart, mb, lb, energies, out);
}